// Round 13
// baseline (920.142 us; speedup 1.0000x reference)
//
#include <hip/hip_runtime.h>
#include <cmath>

#define B_  128
#define T_  512
#define E_  128
#define H_  128
#define G4  512   // 4*H
#define K_  9
#define HP  36    // padded h-quarter stride (floats) — kills 4-way bank alias

// ---------------------------------------------------------------------------
// Kernel 1: input projection GEMM with fused embedding gather.
// proj[b][tc][n] = sum_k embed[sent[b,t]][k] * W_dir[n'][k] + (bih+bhh)[n']
// Tile: 64(M) x 64(N) x 128(K, full), 256 threads, 4x4 micro-tile.
// (R0 version — measured ~190us/dispatch, ~1.16x its DS-pipe floor.
//  Six rewrites (R4/R5/R9/R10/R11/R12) all equal or worse: 8x8 spills,
//  K-slice/occupancy/coalesced-staging/A-only-LDS all neutral-to-slower.
//  FROZEN.)
// ---------------------------------------------------------------------------
__global__ __launch_bounds__(256, 2)
void proj_gemm(const int* __restrict__ sent, const float* __restrict__ embed,
               const float* __restrict__ Wf, const float* __restrict__ Wb,
               const float* __restrict__ bif, const float* __restrict__ bhf,
               const float* __restrict__ bib, const float* __restrict__ bhb,
               float* __restrict__ proj, int t0f, int Tc)
{
  __shared__ __align__(16) float Al[128 * 64];  // [k][m]
  __shared__ __align__(16) float Bl[128 * 64];  // [k][n]
  const int tid   = threadIdx.x;
  const int ntile = blockIdx.x;            // 0..15
  const int mtile = blockIdx.y;
  const int tpb   = Tc >> 6;               // 64-row tiles per batch element
  const int b     = mtile / tpb;
  const int toff  = (mtile - b * tpb) << 6;
  const int dir   = ntile >> 3;
  const int t0    = dir ? (T_ - t0f - Tc) : t0f;
  const float* __restrict__ W = dir ? Wb : Wf;
  const int n0 = (ntile & 7) << 6;         // row offset inside W (0..448)

  {
    const int r  = tid & 63;
    const int kc = tid >> 6;               // 0..3, each covers 32 k's
    const int t  = t0 + toff + r;
    const int vid = sent[b * T_ + t];
    const float* arow = embed + (size_t)vid * E_ + kc * 32;
    const float* brow = W + (size_t)(n0 + r) * E_ + kc * 32;
#pragma unroll
    for (int q = 0; q < 8; ++q) {
      float4 av = *(const float4*)(arow + q * 4);
      float4 bv = *(const float4*)(brow + q * 4);
      int k0 = kc * 32 + q * 4;
      Al[(k0 + 0) * 64 + r] = av.x; Al[(k0 + 1) * 64 + r] = av.y;
      Al[(k0 + 2) * 64 + r] = av.z; Al[(k0 + 3) * 64 + r] = av.w;
      Bl[(k0 + 0) * 64 + r] = bv.x; Bl[(k0 + 1) * 64 + r] = bv.y;
      Bl[(k0 + 2) * 64 + r] = bv.z; Bl[(k0 + 3) * 64 + r] = bv.w;
    }
  }
  __syncthreads();

  const int mg = tid & 15, ng = tid >> 4;
  float acc[4][4] = {};
#pragma unroll 8
  for (int k = 0; k < 128; ++k) {
    float4 a  = *(const float4*)&Al[k * 64 + mg * 4];
    float4 bb = *(const float4*)&Bl[k * 64 + ng * 4];
    acc[0][0] += a.x * bb.x; acc[0][1] += a.x * bb.y; acc[0][2] += a.x * bb.z; acc[0][3] += a.x * bb.w;
    acc[1][0] += a.y * bb.x; acc[1][1] += a.y * bb.y; acc[1][2] += a.y * bb.z; acc[1][3] += a.y * bb.w;
    acc[2][0] += a.z * bb.x; acc[2][1] += a.z * bb.y; acc[2][2] += a.z * bb.z; acc[2][3] += a.z * bb.w;
    acc[3][0] += a.w * bb.x; acc[3][1] += a.w * bb.y; acc[3][2] += a.w * bb.z; acc[3][3] += a.w * bb.w;
  }

  const float* bi = dir ? bib : bif;
  const float* bh = dir ? bhb : bhf;
  const int nl = ng * 4;
  float4 bias;
  bias.x = bi[n0 + nl + 0] + bh[n0 + nl + 0];
  bias.y = bi[n0 + nl + 1] + bh[n0 + nl + 1];
  bias.z = bi[n0 + nl + 2] + bh[n0 + nl + 2];
  bias.w = bi[n0 + nl + 3] + bh[n0 + nl + 3];
#pragma unroll
  for (int i = 0; i < 4; ++i) {
    const int tloc = toff + mg * 4 + i;
    float4 o;
    o.x = acc[i][0] + bias.x; o.y = acc[i][1] + bias.y;
    o.z = acc[i][2] + bias.z; o.w = acc[i][3] + bias.w;
    *(float4*)&proj[((size_t)(b * Tc + tloc)) * 1024 + dir * G4 + n0 + nl] = o;
  }
}

// ---------------------------------------------------------------------------
// Fast, branchless nonlinearities (v_exp_f32 + v_rcp_f32).
// ---------------------------------------------------------------------------
__device__ __forceinline__ float fast_rcp(float x) {
  return __builtin_amdgcn_rcpf(x);
}
__device__ __forceinline__ float fast_sig(float x) {
  return fast_rcp(1.f + __expf(-x));
}
__device__ __forceinline__ float fast_tanh(float x) {
  return 2.f * fast_rcp(1.f + __expf(-2.f * x)) - 1.f;
}

// ---------------------------------------------------------------------------
// Kernel 2: LSTM recurrence — R13: 1024 threads, k-QUARTERED weights.
//   R8 (512 thr, 64-k halves) showed VGPR=84 with 128 live weight floats ->
//   weights in AGPRs; VALU busy 1494 cyc/SIMD/step vs ~650 countable ->
//   AGPR-operand overhead + weak hiding at 2 waves/SIMD.
//   New: lane l = {u:3b | gp:1b | kq:2b}; wave wv owns units wv*8..+7.
//   Each thread: 2 rows x 32 k = 64 weight floats (~95 VGPR total, under
//   the HARD 128-reg cap a 1024-thr block imposes -> true VGPR residency).
//   16 waves = 4/SIMD (2x latency hiding). kq-reduce: shfl_xor(16)+(32);
//   gate exchange: shfl_xor(8). h quarters at padded stride HP=36 so the
//   wave's 4-address ds_read_b128 is bank-conflict-free (R3 lesson).
// Packed-sequence semantics: state frozen + output zeroed where t >= len.
// ---------------------------------------------------------------------------
__global__ __launch_bounds__(1024)
void lstm_chunk(const float* __restrict__ proj,
                const float* __restrict__ Whf, const float* __restrict__ Whb,
                const int* __restrict__ lengths,
                float* __restrict__ hs,
                float* __restrict__ sh, float* __restrict__ sc,
                int t0f, int Tc, int first)
{
  const int dir = blockIdx.x;
  const int b   = blockIdx.y;
  const int tid = threadIdx.x;         // 0..1023
  const int l   = tid & 63;
  const int wv  = tid >> 6;            // 0..15
  const int u   = wv * 8 + (l & 7);    // hidden unit 0..127
  const int gp  = (l >> 3) & 1;        // 0: gates i,f   1: gates g,o
  const int kq  = l >> 4;              // k quarter 0..3
  const int rowA = u + (gp ? 256 : 0); // i or g
  const int rowB = rowA + 128;         // f or o
  const float* __restrict__ Whh = dir ? Whb : Whf;
  __shared__ __align__(16) float h_hist[2][4 * HP];

  float wA[32], wB[32];
  {
    const float* wra = Whh + (size_t)rowA * H_ + kq * 32;
    const float* wrb = Whh + (size_t)rowB * H_ + kq * 32;
#pragma unroll
    for (int k = 0; k < 32; k += 4) {
      float4 va = *(const float4*)(wra + k);
      float4 vb = *(const float4*)(wrb + k);
      wA[k] = va.x; wA[k + 1] = va.y; wA[k + 2] = va.z; wA[k + 3] = va.w;
      wB[k] = vb.x; wB[k + 1] = vb.y; wB[k + 2] = vb.z; wB[k + 3] = vb.w;
    }
  }
#pragma unroll
  for (int k = 0; k < 32; ++k) {
    asm volatile("" : "+v"(wA[k]));
    asm volatile("" : "+v"(wB[k]));
  }

  const int len = lengths[b];
  const int t0  = dir ? (T_ - t0f - Tc) : t0f;
  const float fgp = (float)gp;
  const float kf  = 1.f + fgp;         // 1: sigmoid  2: tanh scaling
  float c = 0.f, h_reg = 0.f;
  if (!first) {
    c     = sc[(dir * B_ + b) * H_ + u];
    h_reg = sh[(dir * B_ + b) * H_ + u];
  }
  if (l < 8) h_hist[1][(u >> 5) * HP + (u & 31)] = h_reg;  // init slot
  __syncthreads();

  const float* projpA = proj + (size_t)b * Tc * 1024 + dir * G4 + rowA;
  const float* projpB = projpA + 128;
  const int tc00 = dir ? (Tc - 1) : 0;
  float pvA = projpA[(size_t)tc00 * 1024];
  float pvB = projpB[(size_t)tc00 * 1024];

  for (int s = 0; s < Tc; ++s) {
    const int tc = dir ? (Tc - 1 - s) : s;
    const int t  = t0 + tc;
    float nvA = 0.f, nvB = 0.f;
    if (s + 1 < Tc) {
      const int tcn = dir ? (Tc - 2 - s) : (s + 1);
      nvA = projpA[(size_t)tcn * 1024];
      nvB = projpB[(size_t)tcn * 1024];
    }
    const float* hp = &h_hist[(s + 1) & 1][kq * HP];   // own k-quarter
    float a0 = 0.f, a1 = 0.f, a2 = 0.f, a3 = 0.f;
#pragma unroll
    for (int k4 = 0; k4 < 8; ++k4) {
      float4 h4 = *(const float4*)&hp[k4 * 4];
      a0 += wA[4 * k4 + 0] * h4.x; a1 += wA[4 * k4 + 1] * h4.y;
      a0 += wA[4 * k4 + 2] * h4.z; a1 += wA[4 * k4 + 3] * h4.w;
      a2 += wB[4 * k4 + 0] * h4.x; a3 += wB[4 * k4 + 1] * h4.y;
      a2 += wB[4 * k4 + 2] * h4.z; a3 += wB[4 * k4 + 3] * h4.w;
    }
    float sA = a0 + a1;
    sA += __shfl_xor(sA, 16); sA += __shfl_xor(sA, 32); sA += pvA;
    float sB = a2 + a3;
    sB += __shfl_xor(sB, 16); sB += __shfl_xor(sB, 32); sB += pvB;
    // gA: sigmoid (gp=0) or tanh (gp=1), branchless; gB: always sigmoid.
    const float gA = kf * fast_rcp(1.f + __expf(-kf * sA)) - fgp;
    const float gB = fast_sig(sB);
    const float xA = __shfl_xor(gA, 8);
    const float xB = __shfl_xor(gB, 8);
    const float gi = gp ? xA : gA;
    const float gf = gp ? xB : gB;
    const float gg = gp ? gA : xA;
    const float go = gp ? gB : xB;
    const float cn = gf * c + gi * gg;
    const float hn = go * fast_tanh(cn);
    const bool  m  = (t < len);
    c     = m ? cn : c;
    h_reg = m ? hn : h_reg;
    if (l < 8) {
      h_hist[s & 1][(u >> 5) * HP + (u & 31)] = h_reg;
      hs[(size_t)(b * T_ + t) * 256 + dir * H_ + u] = m ? hn : 0.f;
    }
    __syncthreads();
    pvA = nvA; pvB = nvB;
  }
  if (l < 8) {                          // wave wv uniquely owns its 8 units
    sh[(dir * B_ + b) * H_ + u] = h_reg;
    sc[(dir * B_ + b) * H_ + u] = c;
  }
}

// ---------------------------------------------------------------------------
// Kernel 3: emissions em[m][k] = hs[m][:] . W_out[k][:] + b_out[k]
// ---------------------------------------------------------------------------
__global__ __launch_bounds__(256)
void emis_kernel(const float* __restrict__ hs, const float* __restrict__ Wout,
                 const float* __restrict__ bout, float* __restrict__ em)
{
  __shared__ __align__(16) float Wl[K_ * 256];
  const int tid = threadIdx.x;
  for (int i = tid; i < K_ * 256; i += 256) Wl[i] = Wout[i];
  __syncthreads();
  const int m = blockIdx.x * 256 + tid;
  const float* h = hs + (size_t)m * 256;
  float acc[K_] = {};
#pragma unroll 4
  for (int kk = 0; kk < 64; ++kk) {
    float4 h4 = *(const float4*)(h + kk * 4);
#pragma unroll
    for (int k9 = 0; k9 < K_; ++k9) {
      float4 w4 = *(const float4*)&Wl[k9 * 256 + kk * 4];
      acc[k9] += h4.x * w4.x + h4.y * w4.y + h4.z * w4.z + h4.w * w4.w;
    }
  }
#pragma unroll
  for (int k9 = 0; k9 < K_; ++k9) em[(size_t)m * K_ + k9] = acc[k9] + bout[k9];
}

// ---------------------------------------------------------------------------
// Kernel 4: Viterbi decode, one 64-lane wave per batch element.
// ---------------------------------------------------------------------------
__global__ __launch_bounds__(64)
void viterbi_kernel(const float* __restrict__ em, const int* __restrict__ lengths,
                    const float* __restrict__ st, const float* __restrict__ en,
                    const float* __restrict__ trans, int* __restrict__ tags)
{
  const int b    = blockIdx.x;
  const int lane = threadIdx.x;
  __shared__ unsigned char hist[(T_ - 1) * 16];
  const int len = lengths[b];
  float tr[K_];
#pragma unroll
  for (int j = 0; j < K_; ++j) tr[j] = (lane < K_) ? trans[j * K_ + lane] : 0.f;
  float s = (lane < K_) ? st[lane] + em[(size_t)(b * T_) * K_ + lane] : -1e30f;
  for (int t = 1; t < len; ++t) {
    float best = -1e30f; int bj = 0;
#pragma unroll
    for (int j = 0; j < K_; ++j) {
      float v = __shfl(s, j) + tr[j];
      if (v > best) { best = v; bj = j; }    // strict > == first-max (argmax)
    }
    if (lane < K_) {
      s = best + em[(size_t)(b * T_ + t) * K_ + lane];
      hist[(t - 1) * 16 + lane] = (unsigned char)bj;
    }
  }
  float fs = (lane < K_) ? s + en[lane] : -1e30f;
  float best = -1e30f; int last = 0;
#pragma unroll
  for (int j = 0; j < K_; ++j) {
    float v = __shfl(fs, j);
    if (v > best) { best = v; last = j; }
  }
  __syncthreads();                            // hist visible to lane 0
  if (lane == 0) {
    int tag = last;
    tags[b * T_ + len - 1] = tag;
    for (int t = len - 2; t >= 0; --t) {
      tag = hist[t * 16 + tag];
      tags[b * T_ + t] = tag;
    }
  }
  for (int t = len + lane; t < T_; t += 64) tags[b * T_ + t] = 0;
}

// ---------------------------------------------------------------------------
extern "C" void kernel_launch(void* const* d_in, const int* in_sizes, int n_in,
                              void* d_out, int out_size, void* d_ws, size_t ws_size,
                              hipStream_t stream)
{
  const int*   sent  = (const int*)d_in[0];
  const int*   lens  = (const int*)d_in[1];
  const float* embed = (const float*)d_in[2];
  const float* Wif   = (const float*)d_in[3];
  const float* Whf   = (const float*)d_in[4];
  const float* bif   = (const float*)d_in[5];
  const float* bhf   = (const float*)d_in[6];
  const float* Wib   = (const float*)d_in[7];
  const float* Whb   = (const float*)d_in[8];
  const float* bib   = (const float*)d_in[9];
  const float* bhb   = (const float*)d_in[10];
  const float* Wout  = (const float*)d_in[11];
  const float* bout  = (const float*)d_in[12];
  const float* stt   = (const float*)d_in[13];
  const float* ent   = (const float*)d_in[14];
  const float* trans = (const float*)d_in[15];
  int* tags = (int*)d_out;

  // workspace layout (floats): hs | em | state_h | state_c | proj(chunked)
  float* ws   = (float*)d_ws;
  float* hs   = ws;                                  // B*T*256   (67.1 MB)
  float* em   = hs + (size_t)B_ * T_ * 256;          // B*T*9     ( 2.4 MB)
  float* sh   = em + (size_t)B_ * T_ * K_;           // 2*B*H carry h
  float* sc   = sh + (size_t)2 * B_ * H_;            // 2*B*H carry c
  float* proj = sc + (size_t)2 * B_ * H_;
  const size_t fixed_bytes = (size_t)(proj - ws) * sizeof(float);

  // largest time-chunk whose proj buffer fits the workspace (floor at 64)
  int Tc = 512;
  while (Tc > 64 && fixed_bytes + (size_t)B_ * Tc * 1024 * sizeof(float) > ws_size)
    Tc >>= 1;

  const int nch = T_ / Tc;
  for (int c2 = 0; c2 < nch; ++c2) {
    const int t0f = c2 * Tc;
    dim3 g1(16, B_ * (Tc >> 6));
    hipLaunchKernelGGL(proj_gemm, g1, dim3(256), 0, stream,
                       sent, embed, Wif, Wib, bif, bhf, bib, bhb, proj, t0f, Tc);
    dim3 g2(2, B_);
    hipLaunchKernelGGL(lstm_chunk, g2, dim3(1024), 0, stream,
                       proj, Whf, Whb, lens, hs, sh, sc, t0f, Tc, (int)(c2 == 0));
  }
  hipLaunchKernelGGL(emis_kernel, dim3((B_ * T_) / 256), dim3(256), 0, stream,
                     hs, Wout, bout, em);
  hipLaunchKernelGGL(viterbi_kernel, dim3(B_), dim3(64), 0, stream,
                     em, lens, stt, ent, trans, tags);
}

// Round 14
// 882.805 us; speedup vs baseline: 1.0423x; 1.0423x over previous
//
#include <hip/hip_runtime.h>
#include <cmath>

#define B_  128
#define T_  512
#define E_  128
#define H_  128
#define G4  512   // 4*H
#define K_  9
#define HP  36    // padded h-quarter stride (floats) — conflict-free quarters

// ---------------------------------------------------------------------------
// Kernel 1: input projection GEMM with fused embedding gather.
// Tile: 64(M) x 64(N) x 128(K), 256 threads, 4x4 micro-tile.
// (R0 version, ~190us/dispatch ≈ 1.16x DS floor. Six rewrites all equal or
//  worse. FROZEN.)
// ---------------------------------------------------------------------------
__global__ __launch_bounds__(256, 2)
void proj_gemm(const int* __restrict__ sent, const float* __restrict__ embed,
               const float* __restrict__ Wf, const float* __restrict__ Wb,
               const float* __restrict__ bif, const float* __restrict__ bhf,
               const float* __restrict__ bib, const float* __restrict__ bhb,
               float* __restrict__ proj, int t0f, int Tc)
{
  __shared__ __align__(16) float Al[128 * 64];  // [k][m]
  __shared__ __align__(16) float Bl[128 * 64];  // [k][n]
  const int tid   = threadIdx.x;
  const int ntile = blockIdx.x;            // 0..15
  const int mtile = blockIdx.y;
  const int tpb   = Tc >> 6;               // 64-row tiles per batch element
  const int b     = mtile / tpb;
  const int toff  = (mtile - b * tpb) << 6;
  const int dir   = ntile >> 3;
  const int t0    = dir ? (T_ - t0f - Tc) : t0f;
  const float* __restrict__ W = dir ? Wb : Wf;
  const int n0 = (ntile & 7) << 6;         // row offset inside W (0..448)

  {
    const int r  = tid & 63;
    const int kc = tid >> 6;               // 0..3, each covers 32 k's
    const int t  = t0 + toff + r;
    const int vid = sent[b * T_ + t];
    const float* arow = embed + (size_t)vid * E_ + kc * 32;
    const float* brow = W + (size_t)(n0 + r) * E_ + kc * 32;
#pragma unroll
    for (int q = 0; q < 8; ++q) {
      float4 av = *(const float4*)(arow + q * 4);
      float4 bv = *(const float4*)(brow + q * 4);
      int k0 = kc * 32 + q * 4;
      Al[(k0 + 0) * 64 + r] = av.x; Al[(k0 + 1) * 64 + r] = av.y;
      Al[(k0 + 2) * 64 + r] = av.z; Al[(k0 + 3) * 64 + r] = av.w;
      Bl[(k0 + 0) * 64 + r] = bv.x; Bl[(k0 + 1) * 64 + r] = bv.y;
      Bl[(k0 + 2) * 64 + r] = bv.z; Bl[(k0 + 3) * 64 + r] = bv.w;
    }
  }
  __syncthreads();

  const int mg = tid & 15, ng = tid >> 4;
  float acc[4][4] = {};
#pragma unroll 8
  for (int k = 0; k < 128; ++k) {
    float4 a  = *(const float4*)&Al[k * 64 + mg * 4];
    float4 bb = *(const float4*)&Bl[k * 64 + ng * 4];
    acc[0][0] += a.x * bb.x; acc[0][1] += a.x * bb.y; acc[0][2] += a.x * bb.z; acc[0][3] += a.x * bb.w;
    acc[1][0] += a.y * bb.x; acc[1][1] += a.y * bb.y; acc[1][2] += a.y * bb.z; acc[1][3] += a.y * bb.w;
    acc[2][0] += a.z * bb.x; acc[2][1] += a.z * bb.y; acc[2][2] += a.z * bb.z; acc[2][3] += a.z * bb.w;
    acc[3][0] += a.w * bb.x; acc[3][1] += a.w * bb.y; acc[3][2] += a.w * bb.z; acc[3][3] += a.w * bb.w;
  }

  const float* bi = dir ? bib : bif;
  const float* bh = dir ? bhb : bhf;
  const int nl = ng * 4;
  float4 bias;
  bias.x = bi[n0 + nl + 0] + bh[n0 + nl + 0];
  bias.y = bi[n0 + nl + 1] + bh[n0 + nl + 1];
  bias.z = bi[n0 + nl + 2] + bh[n0 + nl + 2];
  bias.w = bi[n0 + nl + 3] + bh[n0 + nl + 3];
#pragma unroll
  for (int i = 0; i < 4; ++i) {
    const int tloc = toff + mg * 4 + i;
    float4 o;
    o.x = acc[i][0] + bias.x; o.y = acc[i][1] + bias.y;
    o.z = acc[i][2] + bias.z; o.w = acc[i][3] + bias.w;
    *(float4*)&proj[((size_t)(b * Tc + tloc)) * 1024 + dir * G4 + n0 + nl] = o;
  }
}

// ---------------------------------------------------------------------------
// Fast, branchless nonlinearities (v_exp_f32 + v_rcp_f32).
// ---------------------------------------------------------------------------
__device__ __forceinline__ float fast_rcp(float x) {
  return __builtin_amdgcn_rcpf(x);
}
__device__ __forceinline__ float fast_sig(float x) {
  return fast_rcp(1.f + __expf(-x));
}
__device__ __forceinline__ float fast_tanh(float x) {
  return 2.f * fast_rcp(1.f + __expf(-2.f * x)) - 1.f;
}

// ---------------------------------------------------------------------------
// Kernel 2: LSTM recurrence — R14: 4 gates per thread, k-quartered.
//   R8's 207us is DS-bound: 16 ds_read_b128/thread x 8 waves = 128 DS read
//   instrs/step (~1500cyc) — the minimum for "each lane holds 64 h floats".
//   New layout (512 thr, 8 waves): lane l: unit u = wv*16+(l&15), k-quarter
//   kq = l>>4. Each thread owns ALL 4 gate rows (i,f,g,o) of u x 32 k:
//   8 ds_read_b128/thread -> 64 DS reads/step (HALF). kq-reduce:
//   shfl_xor(16)+shfl_xor(32) per gate (8 shuffles); NO gate-exchange
//   shuffles, no divergent gate select (all lanes identical code). Cell
//   update redundant x4 (identical FP). h quarters at padded stride HP=36:
//   4 group addresses hit disjoint bank quads (R13-validated, 0 conflicts).
// Packed-sequence semantics: state frozen + output zeroed where t >= len.
// ---------------------------------------------------------------------------
__global__ __launch_bounds__(512, 2)
void lstm_chunk(const float* __restrict__ proj,
                const float* __restrict__ Whf, const float* __restrict__ Whb,
                const int* __restrict__ lengths,
                float* __restrict__ hs,
                float* __restrict__ sh, float* __restrict__ sc,
                int t0f, int Tc, int first)
{
  const int dir = blockIdx.x;
  const int b   = blockIdx.y;
  const int tid = threadIdx.x;         // 0..511
  const int l   = tid & 63;
  const int wv  = tid >> 6;            // 0..7
  const int u   = wv * 16 + (l & 15);  // hidden unit 0..127
  const int kq  = l >> 4;              // k quarter 0..3
  const float* __restrict__ Whh = dir ? Whb : Whf;
  __shared__ __align__(16) float h_hist[2][4 * HP];

  float wI[32], wF[32], wG[32], wO[32];
  {
    const float* wi = Whh + (size_t)(u)       * H_ + kq * 32;
    const float* wf = Whh + (size_t)(u + 128) * H_ + kq * 32;
    const float* wg = Whh + (size_t)(u + 256) * H_ + kq * 32;
    const float* wo = Whh + (size_t)(u + 384) * H_ + kq * 32;
#pragma unroll
    for (int k = 0; k < 32; k += 4) {
      float4 vi = *(const float4*)(wi + k);
      float4 vf = *(const float4*)(wf + k);
      float4 vg = *(const float4*)(wg + k);
      float4 vo = *(const float4*)(wo + k);
      wI[k] = vi.x; wI[k + 1] = vi.y; wI[k + 2] = vi.z; wI[k + 3] = vi.w;
      wF[k] = vf.x; wF[k + 1] = vf.y; wF[k + 2] = vf.z; wF[k + 3] = vf.w;
      wG[k] = vg.x; wG[k + 1] = vg.y; wG[k + 2] = vg.z; wG[k + 3] = vg.w;
      wO[k] = vo.x; wO[k + 1] = vo.y; wO[k + 2] = vo.z; wO[k + 3] = vo.w;
    }
  }
#pragma unroll
  for (int k = 0; k < 32; ++k) {
    asm volatile("" : "+v"(wI[k])); asm volatile("" : "+v"(wF[k]));
    asm volatile("" : "+v"(wG[k])); asm volatile("" : "+v"(wO[k]));
  }

  const int len = lengths[b];
  const int t0  = dir ? (T_ - t0f - Tc) : t0f;
  float c = 0.f, h_reg = 0.f;
  if (!first) {
    c     = sc[(dir * B_ + b) * H_ + u];
    h_reg = sh[(dir * B_ + b) * H_ + u];
  }
  if (l < 16) h_hist[1][(u >> 5) * HP + (u & 31)] = h_reg;  // step-0 slot
  __syncthreads();

  const long stp = dir ? -1024 : 1024;     // proj row walk (floats)
  const float* pp = proj + (size_t)b * Tc * 1024 + dir * G4 + u
                         + (size_t)(dir ? (Tc - 1) : 0) * 1024;
  float pvI = pp[0], pvF = pp[128], pvG = pp[256], pvO = pp[384];

  for (int s = 0; s < Tc; ++s) {
    const int tc = dir ? (Tc - 1 - s) : s;
    const int t  = t0 + tc;
    float nI = 0.f, nF = 0.f, nG = 0.f, nO = 0.f;
    if (s + 1 < Tc) {
      const float* np = pp + stp;
      nI = np[0]; nF = np[128]; nG = np[256]; nO = np[384];
    }
    const float* hp = &h_hist[(s + 1) & 1][kq * HP];   // own k-quarter
    float aI0 = 0.f, aI1 = 0.f, aF0 = 0.f, aF1 = 0.f;
    float aG0 = 0.f, aG1 = 0.f, aO0 = 0.f, aO1 = 0.f;
#pragma unroll
    for (int k4 = 0; k4 < 8; ++k4) {
      float4 h4 = *(const float4*)&hp[k4 * 4];
      aI0 += wI[4 * k4 + 0] * h4.x; aI1 += wI[4 * k4 + 1] * h4.y;
      aI0 += wI[4 * k4 + 2] * h4.z; aI1 += wI[4 * k4 + 3] * h4.w;
      aF0 += wF[4 * k4 + 0] * h4.x; aF1 += wF[4 * k4 + 1] * h4.y;
      aF0 += wF[4 * k4 + 2] * h4.z; aF1 += wF[4 * k4 + 3] * h4.w;
      aG0 += wG[4 * k4 + 0] * h4.x; aG1 += wG[4 * k4 + 1] * h4.y;
      aG0 += wG[4 * k4 + 2] * h4.z; aG1 += wG[4 * k4 + 3] * h4.w;
      aO0 += wO[4 * k4 + 0] * h4.x; aO1 += wO[4 * k4 + 1] * h4.y;
      aO0 += wO[4 * k4 + 2] * h4.z; aO1 += wO[4 * k4 + 3] * h4.w;
    }
    float sI = aI0 + aI1; sI += __shfl_xor(sI, 16); sI += __shfl_xor(sI, 32);
    float sF = aF0 + aF1; sF += __shfl_xor(sF, 16); sF += __shfl_xor(sF, 32);
    float sG = aG0 + aG1; sG += __shfl_xor(sG, 16); sG += __shfl_xor(sG, 32);
    float sO = aO0 + aO1; sO += __shfl_xor(sO, 16); sO += __shfl_xor(sO, 32);
    const float gi = fast_sig(sI + pvI);
    const float gf = fast_sig(sF + pvF);
    const float gg = fast_tanh(sG + pvG);
    const float go = fast_sig(sO + pvO);
    const float cn = gf * c + gi * gg;
    const float hn = go * fast_tanh(cn);
    const bool  m  = (t < len);
    c     = m ? cn : c;
    h_reg = m ? hn : h_reg;
    if (l < 16) {
      h_hist[s & 1][(u >> 5) * HP + (u & 31)] = h_reg;
      hs[(size_t)(b * T_ + t) * 256 + dir * H_ + u] = m ? hn : 0.f;
    }
    __syncthreads();
    pp += stp;
    pvI = nI; pvF = nF; pvG = nG; pvO = nO;
  }
  if (l < 16) {                        // wave wv uniquely owns its 16 units
    sh[(dir * B_ + b) * H_ + u] = h_reg;
    sc[(dir * B_ + b) * H_ + u] = c;
  }
}

// ---------------------------------------------------------------------------
// Kernel 3: emissions em[m][k] = hs[m][:] . W_out[k][:] + b_out[k]
// ---------------------------------------------------------------------------
__global__ __launch_bounds__(256)
void emis_kernel(const float* __restrict__ hs, const float* __restrict__ Wout,
                 const float* __restrict__ bout, float* __restrict__ em)
{
  __shared__ __align__(16) float Wl[K_ * 256];
  const int tid = threadIdx.x;
  for (int i = tid; i < K_ * 256; i += 256) Wl[i] = Wout[i];
  __syncthreads();
  const int m = blockIdx.x * 256 + tid;
  const float* h = hs + (size_t)m * 256;
  float acc[K_] = {};
#pragma unroll 4
  for (int kk = 0; kk < 64; ++kk) {
    float4 h4 = *(const float4*)(h + kk * 4);
#pragma unroll
    for (int k9 = 0; k9 < K_; ++k9) {
      float4 w4 = *(const float4*)&Wl[k9 * 256 + kk * 4];
      acc[k9] += h4.x * w4.x + h4.y * w4.y + h4.z * w4.z + h4.w * w4.w;
    }
  }
#pragma unroll
  for (int k9 = 0; k9 < K_; ++k9) em[(size_t)m * K_ + k9] = acc[k9] + bout[k9];
}

// ---------------------------------------------------------------------------
// Kernel 4: Viterbi decode, one 64-lane wave per batch element.
// ---------------------------------------------------------------------------
__global__ __launch_bounds__(64)
void viterbi_kernel(const float* __restrict__ em, const int* __restrict__ lengths,
                    const float* __restrict__ st, const float* __restrict__ en,
                    const float* __restrict__ trans, int* __restrict__ tags)
{
  const int b    = blockIdx.x;
  const int lane = threadIdx.x;
  __shared__ unsigned char hist[(T_ - 1) * 16];
  const int len = lengths[b];
  float tr[K_];
#pragma unroll
  for (int j = 0; j < K_; ++j) tr[j] = (lane < K_) ? trans[j * K_ + lane] : 0.f;
  float s = (lane < K_) ? st[lane] + em[(size_t)(b * T_) * K_ + lane] : -1e30f;
  for (int t = 1; t < len; ++t) {
    float best = -1e30f; int bj = 0;
#pragma unroll
    for (int j = 0; j < K_; ++j) {
      float v = __shfl(s, j) + tr[j];
      if (v > best) { best = v; bj = j; }    // strict > == first-max (argmax)
    }
    if (lane < K_) {
      s = best + em[(size_t)(b * T_ + t) * K_ + lane];
      hist[(t - 1) * 16 + lane] = (unsigned char)bj;
    }
  }
  float fs = (lane < K_) ? s + en[lane] : -1e30f;
  float best = -1e30f; int last = 0;
#pragma unroll
  for (int j = 0; j < K_; ++j) {
    float v = __shfl(fs, j);
    if (v > best) { best = v; last = j; }
  }
  __syncthreads();                            // hist visible to lane 0
  if (lane == 0) {
    int tag = last;
    tags[b * T_ + len - 1] = tag;
    for (int t = len - 2; t >= 0; --t) {
      tag = hist[t * 16 + tag];
      tags[b * T_ + t] = tag;
    }
  }
  for (int t = len + lane; t < T_; t += 64) tags[b * T_ + t] = 0;
}

// ---------------------------------------------------------------------------
extern "C" void kernel_launch(void* const* d_in, const int* in_sizes, int n_in,
                              void* d_out, int out_size, void* d_ws, size_t ws_size,
                              hipStream_t stream)
{
  const int*   sent  = (const int*)d_in[0];
  const int*   lens  = (const int*)d_in[1];
  const float* embed = (const float*)d_in[2];
  const float* Wif   = (const float*)d_in[3];
  const float* Whf   = (const float*)d_in[4];
  const float* bif   = (const float*)d_in[5];
  const float* bhf   = (const float*)d_in[6];
  const float* Wib   = (const float*)d_in[7];
  const float* Whb   = (const float*)d_in[8];
  const float* bib   = (const float*)d_in[9];
  const float* bhb   = (const float*)d_in[10];
  const float* Wout  = (const float*)d_in[11];
  const float* bout  = (const float*)d_in[12];
  const float* stt   = (const float*)d_in[13];
  const float* ent   = (const float*)d_in[14];
  const float* trans = (const float*)d_in[15];
  int* tags = (int*)d_out;

  // workspace layout (floats): hs | em | state_h | state_c | proj(chunked)
  float* ws   = (float*)d_ws;
  float* hs   = ws;                                  // B*T*256   (67.1 MB)
  float* em   = hs + (size_t)B_ * T_ * 256;          // B*T*9     ( 2.4 MB)
  float* sh   = em + (size_t)B_ * T_ * K_;           // 2*B*H carry h
  float* sc   = sh + (size_t)2 * B_ * H_;            // 2*B*H carry c
  float* proj = sc + (size_t)2 * B_ * H_;
  const size_t fixed_bytes = (size_t)(proj - ws) * sizeof(float);

  // largest time-chunk whose proj buffer fits the workspace (floor at 64)
  int Tc = 512;
  while (Tc > 64 && fixed_bytes + (size_t)B_ * Tc * 1024 * sizeof(float) > ws_size)
    Tc >>= 1;

  const int nch = T_ / Tc;
  for (int c2 = 0; c2 < nch; ++c2) {
    const int t0f = c2 * Tc;
    dim3 g1(16, B_ * (Tc >> 6));
    hipLaunchKernelGGL(proj_gemm, g1, dim3(256), 0, stream,
                       sent, embed, Wif, Wib, bif, bhf, bib, bhb, proj, t0f, Tc);
    dim3 g2(2, B_);
    hipLaunchKernelGGL(lstm_chunk, g2, dim3(512), 0, stream,
                       proj, Whf, Whb, lens, hs, sh, sc, t0f, Tc, (int)(c2 == 0));
  }
  hipLaunchKernelGGL(emis_kernel, dim3((B_ * T_) / 256), dim3(256), 0, stream,
                     hs, Wout, bout, em);
  hipLaunchKernelGGL(viterbi_kernel, dim3(B_), dim3(64), 0, stream,
                     em, lens, stt, ent, trans, tags);
}

// Round 15
// 853.806 us; speedup vs baseline: 1.0777x; 1.0340x over previous
//
#include <hip/hip_runtime.h>
#include <cmath>

#define B_  128
#define T_  512
#define E_  128
#define H_  128
#define G4  512   // 4*H
#define K_  9

// ---------------------------------------------------------------------------
// Kernel 1: input projection GEMM with fused embedding gather.
// proj[b][tc][n] = sum_k embed[sent[b,t]][k] * W_dir[n'][k] + (bih+bhh)[n']
// Tile: 64(M) x 64(N) x 128(K, full), 256 threads, 4x4 micro-tile.
// (R0 version, ~190us/dispatch ≈ 1.16x its DS-pipe floor. Six rewrites
//  (R4/R5/R9/R10/R11/R12) all equal or worse. FROZEN.)
// ---------------------------------------------------------------------------
__global__ __launch_bounds__(256, 2)
void proj_gemm(const int* __restrict__ sent, const float* __restrict__ embed,
               const float* __restrict__ Wf, const float* __restrict__ Wb,
               const float* __restrict__ bif, const float* __restrict__ bhf,
               const float* __restrict__ bib, const float* __restrict__ bhb,
               float* __restrict__ proj, int t0f, int Tc)
{
  __shared__ __align__(16) float Al[128 * 64];  // [k][m]
  __shared__ __align__(16) float Bl[128 * 64];  // [k][n]
  const int tid   = threadIdx.x;
  const int ntile = blockIdx.x;            // 0..15
  const int mtile = blockIdx.y;
  const int tpb   = Tc >> 6;               // 64-row tiles per batch element
  const int b     = mtile / tpb;
  const int toff  = (mtile - b * tpb) << 6;
  const int dir   = ntile >> 3;
  const int t0    = dir ? (T_ - t0f - Tc) : t0f;
  const float* __restrict__ W = dir ? Wb : Wf;
  const int n0 = (ntile & 7) << 6;         // row offset inside W (0..448)

  {
    const int r  = tid & 63;
    const int kc = tid >> 6;               // 0..3, each covers 32 k's
    const int t  = t0 + toff + r;
    const int vid = sent[b * T_ + t];
    const float* arow = embed + (size_t)vid * E_ + kc * 32;
    const float* brow = W + (size_t)(n0 + r) * E_ + kc * 32;
#pragma unroll
    for (int q = 0; q < 8; ++q) {
      float4 av = *(const float4*)(arow + q * 4);
      float4 bv = *(const float4*)(brow + q * 4);
      int k0 = kc * 32 + q * 4;
      Al[(k0 + 0) * 64 + r] = av.x; Al[(k0 + 1) * 64 + r] = av.y;
      Al[(k0 + 2) * 64 + r] = av.z; Al[(k0 + 3) * 64 + r] = av.w;
      Bl[(k0 + 0) * 64 + r] = bv.x; Bl[(k0 + 1) * 64 + r] = bv.y;
      Bl[(k0 + 2) * 64 + r] = bv.z; Bl[(k0 + 3) * 64 + r] = bv.w;
    }
  }
  __syncthreads();

  const int mg = tid & 15, ng = tid >> 4;
  float acc[4][4] = {};
#pragma unroll 8
  for (int k = 0; k < 128; ++k) {
    float4 a  = *(const float4*)&Al[k * 64 + mg * 4];
    float4 bb = *(const float4*)&Bl[k * 64 + ng * 4];
    acc[0][0] += a.x * bb.x; acc[0][1] += a.x * bb.y; acc[0][2] += a.x * bb.z; acc[0][3] += a.x * bb.w;
    acc[1][0] += a.y * bb.x; acc[1][1] += a.y * bb.y; acc[1][2] += a.y * bb.z; acc[1][3] += a.y * bb.w;
    acc[2][0] += a.z * bb.x; acc[2][1] += a.z * bb.y; acc[2][2] += a.z * bb.z; acc[2][3] += a.z * bb.w;
    acc[3][0] += a.w * bb.x; acc[3][1] += a.w * bb.y; acc[3][2] += a.w * bb.z; acc[3][3] += a.w * bb.w;
  }

  const float* bi = dir ? bib : bif;
  const float* bh = dir ? bhb : bhf;
  const int nl = ng * 4;
  float4 bias;
  bias.x = bi[n0 + nl + 0] + bh[n0 + nl + 0];
  bias.y = bi[n0 + nl + 1] + bh[n0 + nl + 1];
  bias.z = bi[n0 + nl + 2] + bh[n0 + nl + 2];
  bias.w = bi[n0 + nl + 3] + bh[n0 + nl + 3];
#pragma unroll
  for (int i = 0; i < 4; ++i) {
    const int tloc = toff + mg * 4 + i;
    float4 o;
    o.x = acc[i][0] + bias.x; o.y = acc[i][1] + bias.y;
    o.z = acc[i][2] + bias.z; o.w = acc[i][3] + bias.w;
    *(float4*)&proj[((size_t)(b * Tc + tloc)) * 1024 + dir * G4 + n0 + nl] = o;
  }
}

// ---------------------------------------------------------------------------
// Fast, branchless nonlinearities (v_exp_f32 + v_rcp_f32).
// ---------------------------------------------------------------------------
__device__ __forceinline__ float fast_rcp(float x) {
  return __builtin_amdgcn_rcpf(x);
}
__device__ __forceinline__ float fast_sig(float x) {
  return fast_rcp(1.f + __expf(-x));
}
__device__ __forceinline__ float fast_tanh(float x) {
  return 2.f * fast_rcp(1.f + __expf(-2.f * x)) - 1.f;
}

// ---------------------------------------------------------------------------
// Kernel 2: LSTM recurrence (R7 structure + R8 fast gates — measured
// 206-208us; best of five structural variants R2/R7/R13/R14. RESTORED.)
//   512 thr, 8 waves: lane l of wave w: unit u=w*16+(l&15); gp=(l>>4)&1
//   (0:i,f  1:g,o); kh=l>>5 (k half). 2 rows x 64 k per thread; k-halves
//   summed via __shfl_xor(32); gate exchange via __shfl_xor(16); one
//   barrier/step; h_hist double-buffered; branchless unified gate
//   nonlinearity (kf*rcp(1+exp(-kf*x))-gp).
// Packed-sequence semantics: state frozen + output zeroed where t >= len.
// ---------------------------------------------------------------------------
__global__ __launch_bounds__(512, 2)
void lstm_chunk(const float* __restrict__ proj,
                const float* __restrict__ Whf, const float* __restrict__ Whb,
                const int* __restrict__ lengths,
                float* __restrict__ hs,
                float* __restrict__ sh, float* __restrict__ sc,
                int t0f, int Tc, int first)
{
  const int dir = blockIdx.x;
  const int b   = blockIdx.y;
  const int tid = threadIdx.x;
  const int l   = tid & 63;
  const int wv  = tid >> 6;
  const int u   = wv * 16 + (l & 15);      // hidden unit 0..127
  const int gp  = (l >> 4) & 1;            // 0: gates i,f   1: gates g,o
  const int kh  = l >> 5;                  // k half 0/1
  const int rowA = u + (gp ? 256 : 0);     // i or g
  const int rowB = rowA + 128;             // f or o
  const float* __restrict__ Whh = dir ? Whb : Whf;
  __shared__ __align__(16) float h_hist[2][H_];

  float wA[64], wB[64];
  {
    const float* wra = Whh + (size_t)rowA * H_ + kh * 64;
    const float* wrb = Whh + (size_t)rowB * H_ + kh * 64;
#pragma unroll
    for (int k = 0; k < 64; k += 4) {
      float4 va = *(const float4*)(wra + k);
      float4 vb = *(const float4*)(wrb + k);
      wA[k] = va.x; wA[k + 1] = va.y; wA[k + 2] = va.z; wA[k + 3] = va.w;
      wB[k] = vb.x; wB[k + 1] = vb.y; wB[k + 2] = vb.z; wB[k + 3] = vb.w;
    }
  }
#pragma unroll
  for (int k = 0; k < 64; ++k) {
    asm volatile("" : "+v"(wA[k]));
    asm volatile("" : "+v"(wB[k]));
  }

  const int len = lengths[b];
  const int t0  = dir ? (T_ - t0f - Tc) : t0f;
  const float fgp = (float)gp;
  const float kf  = 1.f + fgp;             // 1: sigmoid  2: tanh scaling
  float c = 0.f, h_reg = 0.f;
  if (!first) {
    c     = sc[(dir * B_ + b) * H_ + u];
    h_reg = sh[(dir * B_ + b) * H_ + u];
  }
  if (l < 16) h_hist[1][u] = h_reg;        // slot read by step 0
  __syncthreads();

  const float* projpA = proj + (size_t)b * Tc * 1024 + dir * G4 + rowA;
  const float* projpB = projpA + 128;
  const int tc00 = dir ? (Tc - 1) : 0;
  float pvA = projpA[(size_t)tc00 * 1024];
  float pvB = projpB[(size_t)tc00 * 1024];

  for (int s = 0; s < Tc; ++s) {
    const int tc = dir ? (Tc - 1 - s) : s;
    const int t  = t0 + tc;
    float nvA = 0.f, nvB = 0.f;
    if (s + 1 < Tc) {
      const int tcn = dir ? (Tc - 2 - s) : (s + 1);
      nvA = projpA[(size_t)tcn * 1024];
      nvB = projpB[(size_t)tcn * 1024];
    }
    const float* hp = h_hist[(s + 1) & 1] + kh * 64;   // h_{s-1}, own k-half
    float a0 = 0.f, a1 = 0.f, a2 = 0.f, a3 = 0.f;
#pragma unroll
    for (int k4 = 0; k4 < 16; ++k4) {
      float4 h4 = *(const float4*)&hp[k4 * 4];
      a0 += wA[4 * k4 + 0] * h4.x; a1 += wA[4 * k4 + 1] * h4.y;
      a0 += wA[4 * k4 + 2] * h4.z; a1 += wA[4 * k4 + 3] * h4.w;
      a2 += wB[4 * k4 + 0] * h4.x; a3 += wB[4 * k4 + 1] * h4.y;
      a2 += wB[4 * k4 + 2] * h4.z; a3 += wB[4 * k4 + 3] * h4.w;
    }
    float sA = a0 + a1; sA += __shfl_xor(sA, 32); sA += pvA;
    float sB = a2 + a3; sB += __shfl_xor(sB, 32); sB += pvB;
    // gA: sigmoid (gp=0) or tanh (gp=1), branchless; gB: always sigmoid.
    const float gA = kf * fast_rcp(1.f + __expf(-kf * sA)) - fgp;
    const float gB = fast_sig(sB);
    const float xA = __shfl_xor(gA, 16);
    const float xB = __shfl_xor(gB, 16);
    const float gi = gp ? xA : gA;
    const float gf = gp ? xB : gB;
    const float gg = gp ? gA : xA;
    const float go = gp ? gB : xB;
    const float cn = gf * c + gi * gg;
    const float hn = go * fast_tanh(cn);
    const bool  m  = (t < len);
    c     = m ? cn : c;
    h_reg = m ? hn : h_reg;
    if (l < 16) {
      h_hist[s & 1][u] = h_reg;
      hs[(size_t)(b * T_ + t) * 256 + dir * H_ + u] = m ? hn : 0.f;
    }
    __syncthreads();
    pvA = nvA; pvB = nvB;
  }
  if (l < 16 && wv == (u >> 4)) {          // one writer per unit
    sh[(dir * B_ + b) * H_ + u] = h_reg;
    sc[(dir * B_ + b) * H_ + u] = c;
  }
}

// ---------------------------------------------------------------------------
// Kernel 3: emissions em[m][k] = hs[m][:] . W_out[k][:] + b_out[k]
// ---------------------------------------------------------------------------
__global__ __launch_bounds__(256)
void emis_kernel(const float* __restrict__ hs, const float* __restrict__ Wout,
                 const float* __restrict__ bout, float* __restrict__ em)
{
  __shared__ __align__(16) float Wl[K_ * 256];
  const int tid = threadIdx.x;
  for (int i = tid; i < K_ * 256; i += 256) Wl[i] = Wout[i];
  __syncthreads();
  const int m = blockIdx.x * 256 + tid;
  const float* h = hs + (size_t)m * 256;
  float acc[K_] = {};
#pragma unroll 4
  for (int kk = 0; kk < 64; ++kk) {
    float4 h4 = *(const float4*)(h + kk * 4);
#pragma unroll
    for (int k9 = 0; k9 < K_; ++k9) {
      float4 w4 = *(const float4*)&Wl[k9 * 256 + kk * 4];
      acc[k9] += h4.x * w4.x + h4.y * w4.y + h4.z * w4.z + h4.w * w4.w;
    }
  }
#pragma unroll
  for (int k9 = 0; k9 < K_; ++k9) em[(size_t)m * K_ + k9] = acc[k9] + bout[k9];
}

// ---------------------------------------------------------------------------
// Kernel 4: Viterbi decode, one 64-lane wave per batch element.
// ---------------------------------------------------------------------------
__global__ __launch_bounds__(64)
void viterbi_kernel(const float* __restrict__ em, const int* __restrict__ lengths,
                    const float* __restrict__ st, const float* __restrict__ en,
                    const float* __restrict__ trans, int* __restrict__ tags)
{
  const int b    = blockIdx.x;
  const int lane = threadIdx.x;
  __shared__ unsigned char hist[(T_ - 1) * 16];
  const int len = lengths[b];
  float tr[K_];
#pragma unroll
  for (int j = 0; j < K_; ++j) tr[j] = (lane < K_) ? trans[j * K_ + lane] : 0.f;
  float s = (lane < K_) ? st[lane] + em[(size_t)(b * T_) * K_ + lane] : -1e30f;
  for (int t = 1; t < len; ++t) {
    float best = -1e30f; int bj = 0;
#pragma unroll
    for (int j = 0; j < K_; ++j) {
      float v = __shfl(s, j) + tr[j];
      if (v > best) { best = v; bj = j; }    // strict > == first-max (argmax)
    }
    if (lane < K_) {
      s = best + em[(size_t)(b * T_ + t) * K_ + lane];
      hist[(t - 1) * 16 + lane] = (unsigned char)bj;
    }
  }
  float fs = (lane < K_) ? s + en[lane] : -1e30f;
  float best = -1e30f; int last = 0;
#pragma unroll
  for (int j = 0; j < K_; ++j) {
    float v = __shfl(fs, j);
    if (v > best) { best = v; last = j; }
  }
  __syncthreads();                            // hist visible to lane 0
  if (lane == 0) {
    int tag = last;
    tags[b * T_ + len - 1] = tag;
    for (int t = len - 2; t >= 0; --t) {
      tag = hist[t * 16 + tag];
      tags[b * T_ + t] = tag;
    }
  }
  for (int t = len + lane; t < T_; t += 64) tags[b * T_ + t] = 0;
}

// ---------------------------------------------------------------------------
extern "C" void kernel_launch(void* const* d_in, const int* in_sizes, int n_in,
                              void* d_out, int out_size, void* d_ws, size_t ws_size,
                              hipStream_t stream)
{
  const int*   sent  = (const int*)d_in[0];
  const int*   lens  = (const int*)d_in[1];
  const float* embed = (const float*)d_in[2];
  const float* Wif   = (const float*)d_in[3];
  const float* Whf   = (const float*)d_in[4];
  const float* bif   = (const float*)d_in[5];
  const float* bhf   = (const float*)d_in[6];
  const float* Wib   = (const float*)d_in[7];
  const float* Whb   = (const float*)d_in[8];
  const float* bib   = (const float*)d_in[9];
  const float* bhb   = (const float*)d_in[10];
  const float* Wout  = (const float*)d_in[11];
  const float* bout  = (const float*)d_in[12];
  const float* stt   = (const float*)d_in[13];
  const float* ent   = (const float*)d_in[14];
  const float* trans = (const float*)d_in[15];
  int* tags = (int*)d_out;

  // workspace layout (floats): hs | em | state_h | state_c | proj(chunked)
  float* ws   = (float*)d_ws;
  float* hs   = ws;                                  // B*T*256   (67.1 MB)
  float* em   = hs + (size_t)B_ * T_ * 256;          // B*T*9     ( 2.4 MB)
  float* sh   = em + (size_t)B_ * T_ * K_;           // 2*B*H carry h
  float* sc   = sh + (size_t)2 * B_ * H_;            // 2*B*H carry c
  float* proj = sc + (size_t)2 * B_ * H_;
  const size_t fixed_bytes = (size_t)(proj - ws) * sizeof(float);

  // largest time-chunk whose proj buffer fits the workspace (floor at 64)
  int Tc = 512;
  while (Tc > 64 && fixed_bytes + (size_t)B_ * Tc * 1024 * sizeof(float) > ws_size)
    Tc >>= 1;

  const int nch = T_ / Tc;
  for (int c2 = 0; c2 < nch; ++c2) {
    const int t0f = c2 * Tc;
    dim3 g1(16, B_ * (Tc >> 6));
    hipLaunchKernelGGL(proj_gemm, g1, dim3(256), 0, stream,
                       sent, embed, Wif, Wib, bif, bhf, bib, bhb, proj, t0f, Tc);
    dim3 g2(2, B_);
    hipLaunchKernelGGL(lstm_chunk, g2, dim3(512), 0, stream,
                       proj, Whf, Whb, lens, hs, sh, sc, t0f, Tc, (int)(c2 == 0));
  }
  hipLaunchKernelGGL(emis_kernel, dim3((B_ * T_) / 256), dim3(256), 0, stream,
                     hs, Wout, bout, em);
  hipLaunchKernelGGL(viterbi_kernel, dim3(B_), dim3(64), 0, stream,
                     em, lens, stt, ent, trans, tags);
}